// Round 1
// baseline (681.145 us; speedup 1.0000x reference)
//
#include <hip/hip_runtime.h>

#define NDIM  48
#define PLANE 2304      // 48*48
#define NVOL  110592    // 48^3
#define NHALF 55296     // NVOL/2
#define TWO_PI 6.28318530717958647692f

// ---------------------------------------------------------------------------
// Build cas tables in LDS: cas48[m] = cos(2pi m/48) + sin(2pi m/48),
// casT[j*48+k] = cas48[(j*k)%48]. Caller must __syncthreads() afterwards
// (we sync once internally between the two phases).
// ---------------------------------------------------------------------------
__device__ __forceinline__ void build_cas(float* cas48, float* casT, int tid) {
    if (tid < 48) {
        float ang = (float)tid * (TWO_PI / 48.0f);
        cas48[tid] = cosf(ang) + sinf(ang);
    }
    __syncthreads();
    for (int idx = tid; idx < 2304; idx += 256) {
        int j = idx / 48, k = idx % 48;
        casT[idx] = cas48[(j * k) % 48];
    }
}

// ---------------------------------------------------------------------------
// Separable cas transform along the W axis (stride 1).
// in/out viewed as [V][48d][48h][48w]; block = (d, v). Only rows h < hcount
// are processed/written; the sum runs over j < jcount.
// out[v][d][h][k] = sum_j in[v][d][h][j] * cas(2pi jk/48)
// ---------------------------------------------------------------------------
__global__ void __launch_bounds__(256) cas_w_kernel(const float* __restrict__ in,
                                                    float* __restrict__ out,
                                                    int hcount, int jcount) {
    __shared__ __align__(16) float cas48[48];
    __shared__ __align__(16) float casT[2304];
    __shared__ __align__(16) float tile[2304];
    const int tid = threadIdx.x;
    const int d = blockIdx.x, v = blockIdx.y;
    const size_t base = (size_t)v * NVOL + (size_t)d * PLANE;

    build_cas(cas48, casT, tid);
    for (int idx = tid; idx < hcount * 48; idx += 256)
        tile[idx] = in[base + idx];
    __syncthreads();

    const float4* casT4 = reinterpret_cast<const float4*>(casT);
    float4* out4 = reinterpret_cast<float4*>(out + base);
    const int nout4 = hcount * 12;
    for (int o4 = tid; o4 < nout4; o4 += 256) {
        int h = o4 / 12, kq = o4 % 12;
        float4 acc = make_float4(0.f, 0.f, 0.f, 0.f);
        #pragma unroll 4
        for (int j = 0; j < jcount; ++j) {
            float  t = tile[h * 48 + j];
            float4 c = casT4[j * 12 + kq];
            acc.x = fmaf(t, c.x, acc.x);
            acc.y = fmaf(t, c.y, acc.y);
            acc.z = fmaf(t, c.z, acc.z);
            acc.w = fmaf(t, c.w, acc.w);
        }
        out4[h * 12 + kq] = acc;
    }
}

// ---------------------------------------------------------------------------
// Separable cas transform along the H axis (stride 48). Block = (d, v).
// out[v][d][k][w] = sum_{h<jcount} in[v][d][h][w] * cas(2pi hk/48)
// ---------------------------------------------------------------------------
__global__ void __launch_bounds__(256) cas_h_kernel(const float* __restrict__ in,
                                                    float* __restrict__ out,
                                                    int jcount) {
    __shared__ __align__(16) float cas48[48];
    __shared__ __align__(16) float casT[2304];
    __shared__ __align__(16) float tile[2304];
    const int tid = threadIdx.x;
    const int d = blockIdx.x, v = blockIdx.y;
    const size_t base = (size_t)v * NVOL + (size_t)d * PLANE;

    build_cas(cas48, casT, tid);
    for (int idx = tid; idx < jcount * 48; idx += 256)
        tile[idx] = in[base + idx];
    __syncthreads();

    const float4* tile4 = reinterpret_cast<const float4*>(tile);
    float4* out4 = reinterpret_cast<float4*>(out + base);
    for (int o4 = tid; o4 < 576; o4 += 256) {
        int k = o4 / 12, wq = o4 % 12;
        float4 acc = make_float4(0.f, 0.f, 0.f, 0.f);
        #pragma unroll 4
        for (int j = 0; j < jcount; ++j) {
            float  c = casT[j * 48 + k];
            float4 t = tile4[j * 12 + wq];
            acc.x = fmaf(t.x, c, acc.x);
            acc.y = fmaf(t.y, c, acc.y);
            acc.z = fmaf(t.z, c, acc.z);
            acc.w = fmaf(t.w, c, acc.w);
        }
        out4[k * 12 + wq] = acc;
    }
}

// ---------------------------------------------------------------------------
// Separable cas transform along the D axis (stride 2304). Block = (h, v).
// out[v][k][h][w] = sum_{d<jcount} in[v][d][h][w] * cas(2pi dk/48)
// ---------------------------------------------------------------------------
__global__ void __launch_bounds__(256) cas_d_kernel(const float* __restrict__ in,
                                                    float* __restrict__ out,
                                                    int jcount) {
    __shared__ __align__(16) float cas48[48];
    __shared__ __align__(16) float casT[2304];
    __shared__ __align__(16) float tile[2304];
    const int tid = threadIdx.x;
    const int h = blockIdx.x, v = blockIdx.y;
    const size_t base = (size_t)v * NVOL + (size_t)h * 48;

    build_cas(cas48, casT, tid);
    for (int idx = tid; idx < jcount * 48; idx += 256) {
        int dd = idx / 48, w = idx % 48;
        tile[idx] = in[base + (size_t)dd * PLANE + w];
    }
    __syncthreads();

    const float4* tile4 = reinterpret_cast<const float4*>(tile);
    for (int o4 = tid; o4 < 576; o4 += 256) {
        int k = o4 / 12, wq = o4 % 12;
        float4 acc = make_float4(0.f, 0.f, 0.f, 0.f);
        #pragma unroll 4
        for (int j = 0; j < jcount; ++j) {
            float  c = casT[j * 48 + k];
            float4 t = tile4[j * 12 + wq];
            acc.x = fmaf(t.x, c, acc.x);
            acc.y = fmaf(t.y, c, acc.y);
            acc.z = fmaf(t.z, c, acc.z);
            acc.w = fmaf(t.w, c, acc.w);
        }
        reinterpret_cast<float4*>(out + base + (size_t)k * PLANE)[wq] = acc;
    }
}

// ---------------------------------------------------------------------------
// Separable -> true 3D DHT:
// H[k1,k2,k3] = scale*( S[k1,k2,-k3] + S[k1,-k2,k3] + S[-k1,k2,k3] - S[-k1,-k2,-k3] )
// (scale includes the 1/2 of the identity; final stage also folds 1/NVOL)
// grid = (432, V); 432*256 == NVOL exactly.
// ---------------------------------------------------------------------------
__global__ void __launch_bounds__(256) combine_kernel(const float* __restrict__ S,
                                                      float* __restrict__ H,
                                                      float scale) {
    const int v = blockIdx.y;
    const int r = blockIdx.x * 256 + threadIdx.x;
    const int k1 = r / PLANE;
    const int r2 = r % PLANE;
    const int k2 = r2 / 48, k3 = r2 % 48;
    const int m1 = (48 - k1) % 48, m2 = (48 - k2) % 48, m3 = (48 - k3) % 48;
    const float* Sv = S + (size_t)v * NVOL;
    float a = Sv[k1 * PLANE + k2 * 48 + m3];
    float b = Sv[k1 * PLANE + m2 * 48 + k3];
    float c = Sv[m1 * PLANE + k2 * 48 + k3];
    float d = Sv[m1 * PLANE + m2 * 48 + m3];
    H[(size_t)v * NVOL + r] = scale * (a + b + c - d);
}

// ---------------------------------------------------------------------------
// Scatter weights [16i][16o][12][12][12] into zero-padded kernel volumes
// A[io][48d][48h][48w] (only the 12^3 corner is ever read downstream, so no
// memset is required).
// ---------------------------------------------------------------------------
__global__ void __launch_bounds__(256) scatter_kernel(const float* __restrict__ w,
                                                      float* __restrict__ A) {
    const int idx = blockIdx.x * 256 + threadIdx.x;
    if (idx >= 16 * 16 * 12 * 12 * 12) return;
    const int io  = idx / 1728;
    const int rem = idx % 1728;
    const int p = rem / 144, q = (rem / 12) % 12, rr = rem % 12;
    A[(size_t)io * NVOL + p * PLANE + q * 48 + rr] = w[idx];
}

// ---------------------------------------------------------------------------
// Pairwise frequency contraction. Leads k = k0+1+kt, kt<8, covering 1..55296
// exactly over 6912 blocks; k=0 handled by zmul_k0_kernel.
// Z[b,o,k]  = 0.5*sum_i [ (X_k+X_kb)*Y_k  + (X_k-X_kb)*Y_kb ]
// Z[b,o,kb] = 0.5*sum_i [ (X_k+X_kb)*Y_kb - (X_k-X_kb)*Y_k  ],  kb = NVOL-k
// X layout [128=b*16+i][NVOL], Y [256=i*16+o][NVOL], Z [128=b*16+o][NVOL].
// ---------------------------------------------------------------------------
__global__ void __launch_bounds__(256) zmul_kernel(const float* __restrict__ X,
                                                   const float* __restrict__ Y,
                                                   float* __restrict__ Z) {
    __shared__ float Xp[8][137], Xm[8][137];
    __shared__ float Yk[8][265], Yf[8][265];
    __shared__ float Zk[8][137], Zf[8][137];
    const int tid = threadIdx.x;
    const int k0 = blockIdx.x * 8;
    const int kt = tid & 7, c0 = tid >> 3;      // c0 in 0..31
    const int k  = k0 + 1 + kt;
    const int kf = NVOL - k;

    for (int c = c0; c < 128; c += 32) {
        float a = X[(size_t)c * NVOL + k];
        float b = X[(size_t)c * NVOL + kf];
        Xp[kt][c] = a + b;
        Xm[kt][c] = a - b;
    }
    for (int c = c0; c < 256; c += 32) {
        Yk[kt][c] = Y[(size_t)c * NVOL + k];
        Yf[kt][c] = Y[(size_t)c * NVOL + kf];
    }
    __syncthreads();

    const int half = tid >> 7;        // 0: k side, 1: flipped side
    const int bo = tid & 127;
    const int b = bo >> 4, o = bo & 15;
    #pragma unroll
    for (int t = 0; t < 8; ++t) {
        float acc = 0.f;
        if (half == 0) {
            #pragma unroll
            for (int i = 0; i < 16; ++i) {
                float xp = Xp[t][b * 16 + i];
                float xm = Xm[t][b * 16 + i];
                acc = fmaf(xp, Yk[t][i * 16 + o], fmaf(xm, Yf[t][i * 16 + o], acc));
            }
            Zk[t][bo] = 0.5f * acc;
        } else {
            #pragma unroll
            for (int i = 0; i < 16; ++i) {
                float xp = Xp[t][b * 16 + i];
                float xm = Xm[t][b * 16 + i];
                acc = fmaf(xp, Yf[t][i * 16 + o], fmaf(-xm, Yk[t][i * 16 + o], acc));
            }
            Zf[t][bo] = 0.5f * acc;
        }
    }
    __syncthreads();

    for (int c = c0; c < 128; c += 32) {
        Z[(size_t)c * NVOL + k]  = Zk[kt][c];
        Z[(size_t)c * NVOL + kf] = Zf[kt][c];
    }
}

__global__ void __launch_bounds__(128) zmul_k0_kernel(const float* __restrict__ X,
                                                      const float* __restrict__ Y,
                                                      float* __restrict__ Z) {
    const int bo = threadIdx.x;           // 128 threads: b*16+o
    const int b = bo >> 4, o = bo & 15;
    float acc = 0.f;
    #pragma unroll
    for (int i = 0; i < 16; ++i)
        acc += X[(size_t)(b * 16 + i) * NVOL] * Y[(size_t)(i * 16 + o) * NVOL];
    Z[(size_t)bo * NVOL] = acc;           // Yodd[0]=0, Yeven[0]=Y[0]
}

// ---------------------------------------------------------------------------
extern "C" void kernel_launch(void* const* d_in, const int* in_sizes, int n_in,
                              void* d_out, int out_size, void* d_ws, size_t ws_size,
                              hipStream_t stream) {
    const float* x = (const float*)d_in[0];     // [8,16,48,48,48]
    const float* w = (const float*)d_in[2];     // [16,16,12,12,12]
    float* out = (float*)d_out;                 // [8,16,48,48,48]

    float* A  = (float*)d_ws;                   // 256*NVOL floats (113 MB)
    float* Bf = A + (size_t)256 * NVOL;         // 256*NVOL floats (113 MB)

    // ---- Y = DHT3(zero-padded kernel), 256 volumes; result lives in A ----
    scatter_kernel<<<(442368 + 255) / 256, 256, 0, stream>>>(w, A);
    cas_w_kernel<<<dim3(12, 256), 256, 0, stream>>>(A, Bf, 12, 12);
    cas_h_kernel<<<dim3(12, 256), 256, 0, stream>>>(Bf, A, 12);
    cas_d_kernel<<<dim3(48, 256), 256, 0, stream>>>(A, Bf, 12);
    combine_kernel<<<dim3(432, 256), 256, 0, stream>>>(Bf, A, 0.5f);

    // ---- X = DHT3(x), 128 volumes; ping-pong inside Bf ----
    float* X1 = Bf;
    float* X2 = Bf + (size_t)128 * NVOL;
    cas_w_kernel<<<dim3(48, 128), 256, 0, stream>>>(x, X1, 48, 48);
    cas_h_kernel<<<dim3(48, 128), 256, 0, stream>>>(X1, X2, 48);
    cas_d_kernel<<<dim3(48, 128), 256, 0, stream>>>(X2, X1, 48);
    combine_kernel<<<dim3(432, 128), 256, 0, stream>>>(X1, X2, 0.5f);   // X := X2

    // ---- Z contraction (X=X2, Y=A) -> X1 ----
    zmul_kernel<<<6912, 256, 0, stream>>>(X2, A, X1);
    zmul_k0_kernel<<<1, 128, 0, stream>>>(X2, A, X1);

    // ---- out = DHT3(Z) / NVOL ----
    cas_w_kernel<<<dim3(48, 128), 256, 0, stream>>>(X1, X2, 48, 48);
    cas_h_kernel<<<dim3(48, 128), 256, 0, stream>>>(X2, X1, 48);
    cas_d_kernel<<<dim3(48, 128), 256, 0, stream>>>(X1, X2, 48);
    combine_kernel<<<dim3(432, 128), 256, 0, stream>>>(X2, out, 0.5f / (float)NVOL);
}

// Round 2
// 624.920 us; speedup vs baseline: 1.0900x; 1.0900x over previous
//
#include <hip/hip_runtime.h>

#define NVOL   110592
#define PLANE  2304
#define TWO_PI 6.28318530717958647692f

__device__ __forceinline__ float dot4(float4 a, float4 b, float acc) {
    acc = fmaf(a.x, b.x, acc); acc = fmaf(a.y, b.y, acc);
    acc = fmaf(a.z, b.z, acc); acc = fmaf(a.w, b.w, acc);
    return acc;
}
__device__ __forceinline__ float dot4m(float4 a, float4 b, float acc) {  // acc -= a.b
    acc = fmaf(-a.x, b.x, acc); acc = fmaf(-a.y, b.y, acc);
    acc = fmaf(-a.z, b.z, acc); acc = fmaf(-a.w, b.w, acc);
    return acc;
}

// ---------------------------------------------------------------------------
// Fused W+H cas transform over one d-plane. Loads LH x LW corner, produces
// full 48x48 transformed plane:  out[kh][kw] = sum_{h<LH,w<LW} in[h][w]
//                                  * cas(2pi w*kw/48) * cas(2pi h*kh/48)
// ---------------------------------------------------------------------------
template<int LH, int LW>
__global__ void __launch_bounds__(192) cas_wh_kernel(const float* __restrict__ in,
                                                     float* __restrict__ out,
                                                     size_t inVol, size_t inPlane, int inRow,
                                                     size_t outVol, size_t outPlane) {
    __shared__ float cas48[48];
    __shared__ __align__(16) float casT[2304];
    __shared__ __align__(16) float tile[LH][48];
    __shared__ __align__(16) float tmp[LH * 48];
    const int tid = threadIdx.x;
    const int d = blockIdx.x, v = blockIdx.y;

    if (tid < 48) { float ang = (float)tid * (TWO_PI / 48.0f); cas48[tid] = cosf(ang) + sinf(ang); }
    __syncthreads();
    for (int idx = tid; idx < 2304; idx += 192) {
        int j = idx / 48, k = idx % 48;
        casT[idx] = cas48[(j * k) % 48];
    }
    const float* ib = in + (size_t)v * inVol + (size_t)d * inPlane;
    for (int idx = tid; idx < LH * LW; idx += 192)
        tile[idx / LW][idx % LW] = ib[(idx / LW) * inRow + (idx % LW)];
    __syncthreads();

    const float4* casT4 = reinterpret_cast<const float4*>(casT);
    float4* tmp4 = reinterpret_cast<float4*>(tmp);
    // stage 1: w-transform, rows h < LH
    for (int o4 = tid; o4 < LH * 12; o4 += 192) {
        int h = o4 / 12, kq = o4 % 12;
        float4 acc = make_float4(0.f, 0.f, 0.f, 0.f);
        #pragma unroll 4
        for (int j = 0; j < LW; ++j) {
            float  t = tile[h][j];
            float4 c = casT4[j * 12 + kq];
            acc.x = fmaf(t, c.x, acc.x); acc.y = fmaf(t, c.y, acc.y);
            acc.z = fmaf(t, c.z, acc.z); acc.w = fmaf(t, c.w, acc.w);
        }
        tmp4[o4] = acc;
    }
    __syncthreads();
    // stage 2: h-transform, all 48 output rows
    float4* ob = reinterpret_cast<float4*>(out + (size_t)v * outVol + (size_t)d * outPlane);
    for (int o4 = tid; o4 < 576; o4 += 192) {
        int kh = o4 / 12, wq = o4 % 12;
        float4 acc = make_float4(0.f, 0.f, 0.f, 0.f);
        #pragma unroll 4
        for (int j = 0; j < LH; ++j) {
            float  c = casT[j * 48 + kh];
            float4 t = tmp4[j * 12 + wq];
            acc.x = fmaf(t.x, c, acc.x); acc.y = fmaf(t.y, c, acc.y);
            acc.z = fmaf(t.z, c, acc.z); acc.w = fmaf(t.w, c, acc.w);
        }
        ob[o4] = acc;
    }
}

// ---------------------------------------------------------------------------
// Fused D-transform + 4-term combine. Block = (h-pair hp, volume v).
// Processes h-columns hA=hp and hB=(48-hp)%48 (all d<JC, all w), d-transforms
// both into SA/SB, then writes the fully-combined DHT rows k2=hA (and k2=hB):
// H[k1,k2,k3] = scale*( S[k1,k2,-k3] + S[k1,-k2,k3] + S[-k1,k2,k3] - S[-k1,-k2,-k3] )
// ---------------------------------------------------------------------------
template<int JC>
__global__ void __launch_bounds__(192) cas_dcomb_kernel(const float* __restrict__ in,
                                                        float* __restrict__ out,
                                                        size_t inVol, float scale) {
    __shared__ float cas48[48];
    __shared__ __align__(16) float casT[2304];
    __shared__ __align__(16) float tA[JC * 48], tB[JC * 48];
    __shared__ __align__(16) float SA[2304], SB[2304];
    const int tid = threadIdx.x;
    const int hp = blockIdx.x, v = blockIdx.y;
    const int hA = hp, hB = (48 - hp) % 48;

    if (tid < 48) { float ang = (float)tid * (TWO_PI / 48.0f); cas48[tid] = cosf(ang) + sinf(ang); }
    __syncthreads();
    for (int idx = tid; idx < 2304; idx += 192) {
        int j = idx / 48, k = idx % 48;
        casT[idx] = cas48[(j * k) % 48];
    }
    const float* ibA = in + (size_t)v * inVol + hA * 48;
    const float* ibB = in + (size_t)v * inVol + hB * 48;
    for (int idx = tid; idx < JC * 48; idx += 192) {
        int dd = idx / 48, w = idx % 48;
        tA[idx] = ibA[(size_t)dd * PLANE + w];
        tB[idx] = ibB[(size_t)dd * PLANE + w];
    }
    __syncthreads();

    const float4* tA4 = reinterpret_cast<const float4*>(tA);
    const float4* tB4 = reinterpret_cast<const float4*>(tB);
    float4* SA4 = reinterpret_cast<float4*>(SA);
    float4* SB4 = reinterpret_cast<float4*>(SB);
    for (int o4 = tid; o4 < 1152; o4 += 192) {
        int sel = (o4 < 576);
        int r = sel ? o4 : o4 - 576;
        int k1 = r / 12, wq = r % 12;
        const float4* src = sel ? tA4 : tB4;
        float4 acc = make_float4(0.f, 0.f, 0.f, 0.f);
        #pragma unroll 4
        for (int dd = 0; dd < JC; ++dd) {
            float  c = casT[dd * 48 + k1];
            float4 t = src[dd * 12 + wq];
            acc.x = fmaf(t.x, c, acc.x); acc.y = fmaf(t.y, c, acc.y);
            acc.z = fmaf(t.z, c, acc.z); acc.w = fmaf(t.w, c, acc.w);
        }
        if (sel) SA4[r] = acc; else SB4[r] = acc;
    }
    __syncthreads();

    float* ob = out + (size_t)v * (size_t)NVOL;
    for (int idx = tid; idx < 4608; idx += 192) {
        int side = (idx >= 2304);
        if (side && hA == hB) continue;
        int r = side ? idx - 2304 : idx;
        int k1 = r / 48, k3 = r % 48;
        int mk1 = (48 - k1) % 48, m3 = (48 - k3) % 48;
        float val;
        if (!side)
            val = SA[k1 * 48 + m3] + SB[k1 * 48 + k3] + SA[mk1 * 48 + k3] - SB[mk1 * 48 + m3];
        else
            val = SB[k1 * 48 + m3] + SA[k1 * 48 + k3] + SB[mk1 * 48 + k3] - SA[mk1 * 48 + m3];
        int k2 = side ? hB : hA;
        ob[k1 * PLANE + k2 * 48 + k3] = scale * val;
    }
}

// ---------------------------------------------------------------------------
// Pairwise frequency contraction, KT=16 leads per block, k = blk*16 + kt
// (k=0 self-paired via select; k=NVOL/2 handled by zmul_self_kernel).
// Z[k]  = 0.5*sum_i [ (Xk+Xkf)*Yk + (Xk-Xkf)*Ykf ]
// Z[kf] = 0.5*sum_i [ (Xk+Xkf)*Ykf - (Xk-Xkf)*Yk ],  kf = NVOL-k
// ---------------------------------------------------------------------------
__global__ void __launch_bounds__(256) zmul_kernel(const float* __restrict__ X,
                                                   const float* __restrict__ Y,
                                                   float* __restrict__ Z) {
    __shared__ __align__(16) float Xp[16 * 132], Xm[16 * 132];   // [t][b*16+i], pad 132
    __shared__ __align__(16) float Yk[16 * 264], Yf[16 * 264];   // [t][o*16+i], pad 264
    const int tid = threadIdx.x;
    const int kt = tid & 15, c0 = tid >> 4;
    const int k0 = blockIdx.x * 16;
    const int k  = k0 + kt;
    const int kf = (k == 0) ? 0 : NVOL - k;

    for (int c = c0; c < 128; c += 16) {
        float a = X[(size_t)c * NVOL + k];
        float b = X[(size_t)c * NVOL + kf];
        Xp[kt * 132 + c] = a + b;
        Xm[kt * 132 + c] = a - b;
    }
    for (int c = c0; c < 256; c += 16) {
        int i = c >> 4, o = c & 15;
        Yk[kt * 264 + o * 16 + i] = Y[(size_t)c * NVOL + k];
        Yf[kt * 264 + o * 16 + i] = Y[(size_t)c * NVOL + kf];
    }
    __syncthreads();

    const int side = tid >> 7;
    const int r = tid & 127;
    const int tq = r >> 5, bb = (r >> 3) & 3, oo = r & 7;  // b in {bb,bb+4}, o in {oo,oo+8}
    const float4* Xp4 = reinterpret_cast<const float4*>(Xp);
    const float4* Xm4 = reinterpret_cast<const float4*>(Xm);
    const float4* Yk4 = reinterpret_cast<const float4*>(Yk);
    const float4* Yf4 = reinterpret_cast<const float4*>(Yf);

    float acc[4][2][2] = {};
    if (side == 0) {
        #pragma unroll
        for (int tt = 0; tt < 4; ++tt) {
            const int t = tq * 4 + tt;
            #pragma unroll
            for (int iq = 0; iq < 4; ++iq) {
                float4 xp0 = Xp4[t * 33 + bb * 4 + iq];
                float4 xp1 = Xp4[t * 33 + (bb + 4) * 4 + iq];
                float4 xm0 = Xm4[t * 33 + bb * 4 + iq];
                float4 xm1 = Xm4[t * 33 + (bb + 4) * 4 + iq];
                float4 y0k = Yk4[t * 66 + oo * 4 + iq];
                float4 y1k = Yk4[t * 66 + (oo + 8) * 4 + iq];
                float4 y0f = Yf4[t * 66 + oo * 4 + iq];
                float4 y1f = Yf4[t * 66 + (oo + 8) * 4 + iq];
                acc[tt][0][0] = dot4(xm0, y0f, dot4(xp0, y0k, acc[tt][0][0]));
                acc[tt][0][1] = dot4(xm0, y1f, dot4(xp0, y1k, acc[tt][0][1]));
                acc[tt][1][0] = dot4(xm1, y0f, dot4(xp1, y0k, acc[tt][1][0]));
                acc[tt][1][1] = dot4(xm1, y1f, dot4(xp1, y1k, acc[tt][1][1]));
            }
        }
        #pragma unroll
        for (int bi = 0; bi < 2; ++bi)
            #pragma unroll
            for (int oi = 0; oi < 2; ++oi) {
                int bo = (bb + bi * 4) * 16 + (oo + oi * 8);
                float4 zv = make_float4(0.5f * acc[0][bi][oi], 0.5f * acc[1][bi][oi],
                                        0.5f * acc[2][bi][oi], 0.5f * acc[3][bi][oi]);
                *reinterpret_cast<float4*>(&Z[(size_t)bo * NVOL + k0 + tq * 4]) = zv;
            }
    } else {
        #pragma unroll
        for (int tt = 0; tt < 4; ++tt) {
            const int t = tq * 4 + tt;
            #pragma unroll
            for (int iq = 0; iq < 4; ++iq) {
                float4 xp0 = Xp4[t * 33 + bb * 4 + iq];
                float4 xp1 = Xp4[t * 33 + (bb + 4) * 4 + iq];
                float4 xm0 = Xm4[t * 33 + bb * 4 + iq];
                float4 xm1 = Xm4[t * 33 + (bb + 4) * 4 + iq];
                float4 y0k = Yk4[t * 66 + oo * 4 + iq];
                float4 y1k = Yk4[t * 66 + (oo + 8) * 4 + iq];
                float4 y0f = Yf4[t * 66 + oo * 4 + iq];
                float4 y1f = Yf4[t * 66 + (oo + 8) * 4 + iq];
                acc[tt][0][0] = dot4m(xm0, y0k, dot4(xp0, y0f, acc[tt][0][0]));
                acc[tt][0][1] = dot4m(xm0, y1k, dot4(xp0, y1f, acc[tt][0][1]));
                acc[tt][1][0] = dot4m(xm1, y0k, dot4(xp1, y0f, acc[tt][1][0]));
                acc[tt][1][1] = dot4m(xm1, y1k, dot4(xp1, y1f, acc[tt][1][1]));
            }
        }
        #pragma unroll
        for (int bi = 0; bi < 2; ++bi)
            #pragma unroll
            for (int oi = 0; oi < 2; ++oi) {
                int bo = (bb + bi * 4) * 16 + (oo + oi * 8);
                #pragma unroll
                for (int tt = 0; tt < 4; ++tt) {
                    int kk = k0 + tq * 4 + tt;
                    int ka = (kk == 0) ? 0 : NVOL - kk;
                    Z[(size_t)bo * NVOL + ka] = 0.5f * acc[tt][bi][oi];
                }
            }
    }
}

__global__ void __launch_bounds__(128) zmul_self_kernel(const float* __restrict__ X,
                                                        const float* __restrict__ Y,
                                                        float* __restrict__ Z) {
    const int bo = threadIdx.x, b = bo >> 4, o = bo & 15;
    const int k = NVOL / 2;
    float acc = 0.f;
    #pragma unroll
    for (int i = 0; i < 16; ++i)
        acc += X[(size_t)(b * 16 + i) * NVOL + k] * Y[(size_t)(i * 16 + o) * NVOL + k];
    Z[(size_t)bo * NVOL + k] = acc;
}

// ---------------------------------------------------------------------------
extern "C" void kernel_launch(void* const* d_in, const int* in_sizes, int n_in,
                              void* d_out, int out_size, void* d_ws, size_t ws_size,
                              hipStream_t stream) {
    const float* x = (const float*)d_in[0];     // [8,16,48,48,48]
    const float* w = (const float*)d_in[2];     // [16,16,12,12,12] -> [io][1728] compact
    float* out = (float*)d_out;                 // [8,16,48,48,48]

    float* HY  = (float*)d_ws;                  // 256*NVOL  (Y DHT, final)
    float* XA  = HY + (size_t)256 * NVOL;       // 128*NVOL
    float* XB  = XA + (size_t)128 * NVOL;       // 128*NVOL
    float* Ywh = XB;                            // 256*27648 floats, aliases XB (freed before dcombX)

    // ---- Y path: weights (compact corner) -> wh planes -> full DHT ----
    cas_wh_kernel<12, 12><<<dim3(12, 256), 192, 0, stream>>>(w, Ywh, 1728, 144, 12, 27648, PLANE);
    cas_dcomb_kernel<12><<<dim3(25, 256), 192, 0, stream>>>(Ywh, HY, 27648, 0.5f);

    // ---- X path ----
    cas_wh_kernel<48, 48><<<dim3(48, 128), 192, 0, stream>>>(x, XA, NVOL, PLANE, 48, NVOL, PLANE);
    cas_dcomb_kernel<48><<<dim3(25, 128), 192, 0, stream>>>(XA, XB, NVOL, 0.5f);  // H_X -> XB

    // ---- Z contraction ----
    zmul_kernel<<<3456, 256, 0, stream>>>(XB, HY, XA);          // Z -> XA
    zmul_self_kernel<<<1, 128, 0, stream>>>(XB, HY, XA);

    // ---- out = DHT3(Z) / NVOL ----
    cas_wh_kernel<48, 48><<<dim3(48, 128), 192, 0, stream>>>(XA, XB, NVOL, PLANE, 48, NVOL, PLANE);
    cas_dcomb_kernel<48><<<dim3(25, 128), 192, 0, stream>>>(XB, out, NVOL, 0.5f / (float)NVOL);
}

// Round 3
// 486.468 us; speedup vs baseline: 1.4002x; 1.2846x over previous
//
#include <hip/hip_runtime.h>

#define NVOL   110592
#define PLANE  2304
#define TWO_PI 6.28318530717958647692f

__device__ __forceinline__ float dot4(float4 a, float4 b, float acc) {
    acc = fmaf(a.x, b.x, acc); acc = fmaf(a.y, b.y, acc);
    acc = fmaf(a.z, b.z, acc); acc = fmaf(a.w, b.w, acc);
    return acc;
}
__device__ __forceinline__ float dot4m(float4 a, float4 b, float acc) {  // acc -= a.b
    acc = fmaf(-a.x, b.x, acc); acc = fmaf(-a.y, b.y, acc);
    acc = fmaf(-a.z, b.z, acc); acc = fmaf(-a.w, b.w, acc);
    return acc;
}

// ---------------------------------------------------------------------------
// Generic (small) fused W+H cas transform — used for the Y/weights path only.
// ---------------------------------------------------------------------------
template<int LH, int LW>
__global__ void __launch_bounds__(192) cas_wh_kernel(const float* __restrict__ in,
                                                     float* __restrict__ out,
                                                     size_t inVol, size_t inPlane, int inRow,
                                                     size_t outVol, size_t outPlane) {
    __shared__ float cas48[48];
    __shared__ __align__(16) float casT[2304];
    __shared__ __align__(16) float tile[LH][48];
    __shared__ __align__(16) float tmp[LH * 48];
    const int tid = threadIdx.x;
    const int d = blockIdx.x, v = blockIdx.y;

    if (tid < 48) { float ang = (float)tid * (TWO_PI / 48.0f); cas48[tid] = cosf(ang) + sinf(ang); }
    __syncthreads();
    for (int idx = tid; idx < 2304; idx += 192) {
        int j = idx / 48, k = idx % 48;
        casT[idx] = cas48[(j * k) % 48];
    }
    const float* ib = in + (size_t)v * inVol + (size_t)d * inPlane;
    for (int idx = tid; idx < LH * LW; idx += 192)
        tile[idx / LW][idx % LW] = ib[(idx / LW) * inRow + (idx % LW)];
    __syncthreads();

    const float4* casT4 = reinterpret_cast<const float4*>(casT);
    float4* tmp4 = reinterpret_cast<float4*>(tmp);
    for (int o4 = tid; o4 < LH * 12; o4 += 192) {
        int h = o4 / 12, kq = o4 % 12;
        float4 acc = make_float4(0.f, 0.f, 0.f, 0.f);
        #pragma unroll 4
        for (int j = 0; j < LW; ++j) {
            float  t = tile[h][j];
            float4 c = casT4[j * 12 + kq];
            acc.x = fmaf(t, c.x, acc.x); acc.y = fmaf(t, c.y, acc.y);
            acc.z = fmaf(t, c.z, acc.z); acc.w = fmaf(t, c.w, acc.w);
        }
        tmp4[o4] = acc;
    }
    __syncthreads();
    float4* ob = reinterpret_cast<float4*>(out + (size_t)v * outVol + (size_t)d * outPlane);
    for (int o4 = tid; o4 < 576; o4 += 192) {
        int kh = o4 / 12, wq = o4 % 12;
        float4 acc = make_float4(0.f, 0.f, 0.f, 0.f);
        #pragma unroll 4
        for (int j = 0; j < LH; ++j) {
            float  c = casT[j * 48 + kh];
            float4 t = tmp4[j * 12 + wq];
            acc.x = fmaf(t.x, c, acc.x); acc.y = fmaf(t.y, c, acc.y);
            acc.z = fmaf(t.z, c, acc.z); acc.w = fmaf(t.w, c, acc.w);
        }
        ob[o4] = acc;
    }
}

// ---------------------------------------------------------------------------
// Register-tiled fused W+H cas transform, full 48x48 planes, 4 planes/block.
// 192 threads: thread -> (plane p, hg, kg); computes a 4h x 12k output tile.
// Stage1: tmp[h][k] = sum_j tile[h][j] cas[j][k]   (tile rows padded to 49)
// Stage2: out[kh][kw] = sum_h cas[h][kh] tmp[h][kw] (tmp rows padded to 52)
// tmp aliases tile (acc register-staged + syncs).
// ---------------------------------------------------------------------------
__global__ void __launch_bounds__(192) cas_wh48(const float* __restrict__ in,
                                                float* __restrict__ out) {
    __shared__ float cas48[48];
    __shared__ __align__(16) float casT[2304];
    __shared__ __align__(16) float buf[4][2496];
    const int tid = threadIdx.x;
    const int bx = blockIdx.x, v = blockIdx.y;

    if (tid < 48) { float ang = (float)tid * (TWO_PI / 48.0f); cas48[tid] = cosf(ang) + sinf(ang); }
    __syncthreads();
    for (int idx = tid; idx < 2304; idx += 192) {
        int j = idx / 48, k = idx % 48;
        casT[idx] = cas48[(j * k) % 48];
    }
    const float* ib = in + (size_t)v * NVOL + (size_t)(bx * 4) * PLANE;
    for (int idx = tid; idx < 2304; idx += 192) {
        int p = idx / 576, r = idx % 576, h = r / 12, q = r % 12;
        float4 t = *reinterpret_cast<const float4*>(ib + (size_t)p * PLANE + h * 48 + q * 4);
        float* dst = &buf[p][h * 49 + q * 4];
        dst[0] = t.x; dst[1] = t.y; dst[2] = t.z; dst[3] = t.w;
    }
    __syncthreads();

    const int p = tid / 48, pp = tid % 48;
    const int hg = pp >> 2, kg = pp & 3;
    float* tile = buf[p];
    const float4* casT4 = reinterpret_cast<const float4*>(casT);

    float4 acc[4][3];
    #pragma unroll
    for (int i = 0; i < 4; ++i)
        #pragma unroll
        for (int q = 0; q < 3; ++q) acc[i][q] = make_float4(0.f, 0.f, 0.f, 0.f);

    #pragma unroll 4
    for (int j = 0; j < 48; ++j) {
        float t0 = tile[(hg * 4 + 0) * 49 + j];
        float t1 = tile[(hg * 4 + 1) * 49 + j];
        float t2 = tile[(hg * 4 + 2) * 49 + j];
        float t3 = tile[(hg * 4 + 3) * 49 + j];
        float4 c[3];
        #pragma unroll
        for (int q = 0; q < 3; ++q) c[q] = casT4[j * 12 + kg * 3 + q];
        #pragma unroll
        for (int q = 0; q < 3; ++q) {
            acc[0][q].x = fmaf(t0, c[q].x, acc[0][q].x); acc[0][q].y = fmaf(t0, c[q].y, acc[0][q].y);
            acc[0][q].z = fmaf(t0, c[q].z, acc[0][q].z); acc[0][q].w = fmaf(t0, c[q].w, acc[0][q].w);
            acc[1][q].x = fmaf(t1, c[q].x, acc[1][q].x); acc[1][q].y = fmaf(t1, c[q].y, acc[1][q].y);
            acc[1][q].z = fmaf(t1, c[q].z, acc[1][q].z); acc[1][q].w = fmaf(t1, c[q].w, acc[1][q].w);
            acc[2][q].x = fmaf(t2, c[q].x, acc[2][q].x); acc[2][q].y = fmaf(t2, c[q].y, acc[2][q].y);
            acc[2][q].z = fmaf(t2, c[q].z, acc[2][q].z); acc[2][q].w = fmaf(t2, c[q].w, acc[2][q].w);
            acc[3][q].x = fmaf(t3, c[q].x, acc[3][q].x); acc[3][q].y = fmaf(t3, c[q].y, acc[3][q].y);
            acc[3][q].z = fmaf(t3, c[q].z, acc[3][q].z); acc[3][q].w = fmaf(t3, c[q].w, acc[3][q].w);
        }
    }
    __syncthreads();
    float* tmp = buf[p];
    #pragma unroll
    for (int i = 0; i < 4; ++i)
        #pragma unroll
        for (int q = 0; q < 3; ++q)
            *reinterpret_cast<float4*>(&tmp[(hg * 4 + i) * 52 + kg * 12 + q * 4]) = acc[i][q];
    __syncthreads();

    float4 acc2[4][3];
    #pragma unroll
    for (int i = 0; i < 4; ++i)
        #pragma unroll
        for (int q = 0; q < 3; ++q) acc2[i][q] = make_float4(0.f, 0.f, 0.f, 0.f);

    #pragma unroll 4
    for (int h = 0; h < 48; ++h) {
        float4 cf = casT4[h * 12 + hg];
        float cfa[4] = {cf.x, cf.y, cf.z, cf.w};
        float4 m[3];
        #pragma unroll
        for (int q = 0; q < 3; ++q) m[q] = *reinterpret_cast<const float4*>(&tmp[h * 52 + kg * 12 + q * 4]);
        #pragma unroll
        for (int i = 0; i < 4; ++i)
            #pragma unroll
            for (int q = 0; q < 3; ++q) {
                acc2[i][q].x = fmaf(cfa[i], m[q].x, acc2[i][q].x);
                acc2[i][q].y = fmaf(cfa[i], m[q].y, acc2[i][q].y);
                acc2[i][q].z = fmaf(cfa[i], m[q].z, acc2[i][q].z);
                acc2[i][q].w = fmaf(cfa[i], m[q].w, acc2[i][q].w);
            }
    }
    float4* ob = reinterpret_cast<float4*>(out + (size_t)v * NVOL + (size_t)(bx * 4 + p) * PLANE);
    #pragma unroll
    for (int i = 0; i < 4; ++i)
        #pragma unroll
        for (int q = 0; q < 3; ++q)
            ob[(hg * 4 + i) * 12 + kg * 3 + q] = acc2[i][q];
}

// ---------------------------------------------------------------------------
// Register-tiled D-transform + 4-term combine. Block = (hp pair, volume).
// 192 threads: m = tid/96 selects column hA/hB; 96 threads per matrix with
// 2k1 x 12w register tiles.  S[k1][w] = sum_d cas[d][k1] * t[d][w].
// Then combine: H[k1,k2,k3] = scale*(S[k1,k2,-k3]+S[k1,-k2,k3]+S[-k1,k2,k3]
//                                    -S[-k1,-k2,-k3])
// ---------------------------------------------------------------------------
template<int JC>
__global__ void __launch_bounds__(192) cas_dcomb2(const float* __restrict__ in,
                                                  float* __restrict__ out,
                                                  size_t inVol, size_t inPlane, float scale) {
    __shared__ float cas48[48];
    __shared__ __align__(16) float casT[2304];
    __shared__ __align__(16) float tAB[2][JC * 52];
    __shared__ __align__(16) float S[2][48 * 52];
    const int tid = threadIdx.x;
    const int hp = blockIdx.x, v = blockIdx.y;
    const int hA = hp, hB = (48 - hp) % 48;

    if (tid < 48) { float ang = (float)tid * (TWO_PI / 48.0f); cas48[tid] = cosf(ang) + sinf(ang); }
    __syncthreads();
    for (int idx = tid; idx < 2304; idx += 192) {
        int j = idx / 48, k = idx % 48;
        casT[idx] = cas48[(j * k) % 48];
    }
    for (int idx = tid; idx < 2 * JC * 12; idx += 192) {
        int mm = idx / (JC * 12), r = idx % (JC * 12);
        int d = r / 12, q = r % 12;
        int hh = mm ? hB : hA;
        float4 t = *reinterpret_cast<const float4*>(in + (size_t)v * inVol + (size_t)d * inPlane + hh * 48 + q * 4);
        *reinterpret_cast<float4*>(&tAB[mm][d * 52 + q * 4]) = t;
    }
    __syncthreads();

    const int m = tid / 96, pth = tid % 96;
    const int k1g = pth >> 2, wg = pth & 3;
    float4 acc[2][3];
    #pragma unroll
    for (int i = 0; i < 2; ++i)
        #pragma unroll
        for (int q = 0; q < 3; ++q) acc[i][q] = make_float4(0.f, 0.f, 0.f, 0.f);

    #pragma unroll 4
    for (int d = 0; d < JC; ++d) {
        float c0 = casT[d * 48 + k1g * 2 + 0];
        float c1 = casT[d * 48 + k1g * 2 + 1];
        float4 t[3];
        #pragma unroll
        for (int q = 0; q < 3; ++q) t[q] = *reinterpret_cast<const float4*>(&tAB[m][d * 52 + wg * 12 + q * 4]);
        #pragma unroll
        for (int q = 0; q < 3; ++q) {
            acc[0][q].x = fmaf(c0, t[q].x, acc[0][q].x); acc[0][q].y = fmaf(c0, t[q].y, acc[0][q].y);
            acc[0][q].z = fmaf(c0, t[q].z, acc[0][q].z); acc[0][q].w = fmaf(c0, t[q].w, acc[0][q].w);
            acc[1][q].x = fmaf(c1, t[q].x, acc[1][q].x); acc[1][q].y = fmaf(c1, t[q].y, acc[1][q].y);
            acc[1][q].z = fmaf(c1, t[q].z, acc[1][q].z); acc[1][q].w = fmaf(c1, t[q].w, acc[1][q].w);
        }
    }
    #pragma unroll
    for (int i = 0; i < 2; ++i)
        #pragma unroll
        for (int q = 0; q < 3; ++q)
            *reinterpret_cast<float4*>(&S[m][(k1g * 2 + i) * 52 + wg * 12 + q * 4]) = acc[i][q];
    __syncthreads();

    float* ob = out + (size_t)v * (size_t)NVOL;
    for (int idx = tid; idx < 4608; idx += 192) {
        int side = (idx >= 2304);
        if (side && hA == hB) continue;
        int r = side ? idx - 2304 : idx;
        int k1 = r / 48, k3 = r % 48;
        int mk1 = (48 - k1) % 48, m3 = (48 - k3) % 48;
        float val;
        if (!side)
            val = S[0][k1 * 52 + m3] + S[1][k1 * 52 + k3] + S[0][mk1 * 52 + k3] - S[1][mk1 * 52 + m3];
        else
            val = S[1][k1 * 52 + m3] + S[0][k1 * 52 + k3] + S[1][mk1 * 52 + k3] - S[0][mk1 * 52 + m3];
        int k2 = side ? hB : hA;
        ob[k1 * PLANE + k2 * 48 + k3] = scale * val;
    }
}

// ---------------------------------------------------------------------------
// Pairwise frequency contraction (unchanged from R2).
// ---------------------------------------------------------------------------
__global__ void __launch_bounds__(256) zmul_kernel(const float* __restrict__ X,
                                                   const float* __restrict__ Y,
                                                   float* __restrict__ Z) {
    __shared__ __align__(16) float Xp[16 * 132], Xm[16 * 132];
    __shared__ __align__(16) float Yk[16 * 264], Yf[16 * 264];
    const int tid = threadIdx.x;
    const int kt = tid & 15, c0 = tid >> 4;
    const int k0 = blockIdx.x * 16;
    const int k  = k0 + kt;
    const int kf = (k == 0) ? 0 : NVOL - k;

    for (int c = c0; c < 128; c += 16) {
        float a = X[(size_t)c * NVOL + k];
        float b = X[(size_t)c * NVOL + kf];
        Xp[kt * 132 + c] = a + b;
        Xm[kt * 132 + c] = a - b;
    }
    for (int c = c0; c < 256; c += 16) {
        int i = c >> 4, o = c & 15;
        Yk[kt * 264 + o * 16 + i] = Y[(size_t)c * NVOL + k];
        Yf[kt * 264 + o * 16 + i] = Y[(size_t)c * NVOL + kf];
    }
    __syncthreads();

    const int side = tid >> 7;
    const int r = tid & 127;
    const int tq = r >> 5, bb = (r >> 3) & 3, oo = r & 7;
    const float4* Xp4 = reinterpret_cast<const float4*>(Xp);
    const float4* Xm4 = reinterpret_cast<const float4*>(Xm);
    const float4* Yk4 = reinterpret_cast<const float4*>(Yk);
    const float4* Yf4 = reinterpret_cast<const float4*>(Yf);

    float acc[4][2][2] = {};
    if (side == 0) {
        #pragma unroll
        for (int tt = 0; tt < 4; ++tt) {
            const int t = tq * 4 + tt;
            #pragma unroll
            for (int iq = 0; iq < 4; ++iq) {
                float4 xp0 = Xp4[t * 33 + bb * 4 + iq];
                float4 xp1 = Xp4[t * 33 + (bb + 4) * 4 + iq];
                float4 xm0 = Xm4[t * 33 + bb * 4 + iq];
                float4 xm1 = Xm4[t * 33 + (bb + 4) * 4 + iq];
                float4 y0k = Yk4[t * 66 + oo * 4 + iq];
                float4 y1k = Yk4[t * 66 + (oo + 8) * 4 + iq];
                float4 y0f = Yf4[t * 66 + oo * 4 + iq];
                float4 y1f = Yf4[t * 66 + (oo + 8) * 4 + iq];
                acc[tt][0][0] = dot4(xm0, y0f, dot4(xp0, y0k, acc[tt][0][0]));
                acc[tt][0][1] = dot4(xm0, y1f, dot4(xp0, y1k, acc[tt][0][1]));
                acc[tt][1][0] = dot4(xm1, y0f, dot4(xp1, y0k, acc[tt][1][0]));
                acc[tt][1][1] = dot4(xm1, y1f, dot4(xp1, y1k, acc[tt][1][1]));
            }
        }
        #pragma unroll
        for (int bi = 0; bi < 2; ++bi)
            #pragma unroll
            for (int oi = 0; oi < 2; ++oi) {
                int bo = (bb + bi * 4) * 16 + (oo + oi * 8);
                float4 zv = make_float4(0.5f * acc[0][bi][oi], 0.5f * acc[1][bi][oi],
                                        0.5f * acc[2][bi][oi], 0.5f * acc[3][bi][oi]);
                *reinterpret_cast<float4*>(&Z[(size_t)bo * NVOL + k0 + tq * 4]) = zv;
            }
    } else {
        #pragma unroll
        for (int tt = 0; tt < 4; ++tt) {
            const int t = tq * 4 + tt;
            #pragma unroll
            for (int iq = 0; iq < 4; ++iq) {
                float4 xp0 = Xp4[t * 33 + bb * 4 + iq];
                float4 xp1 = Xp4[t * 33 + (bb + 4) * 4 + iq];
                float4 xm0 = Xm4[t * 33 + bb * 4 + iq];
                float4 xm1 = Xm4[t * 33 + (bb + 4) * 4 + iq];
                float4 y0k = Yk4[t * 66 + oo * 4 + iq];
                float4 y1k = Yk4[t * 66 + (oo + 8) * 4 + iq];
                float4 y0f = Yf4[t * 66 + oo * 4 + iq];
                float4 y1f = Yf4[t * 66 + (oo + 8) * 4 + iq];
                acc[tt][0][0] = dot4m(xm0, y0k, dot4(xp0, y0f, acc[tt][0][0]));
                acc[tt][0][1] = dot4m(xm0, y1k, dot4(xp0, y1f, acc[tt][0][1]));
                acc[tt][1][0] = dot4m(xm1, y0k, dot4(xp1, y0f, acc[tt][1][0]));
                acc[tt][1][1] = dot4m(xm1, y1k, dot4(xp1, y1f, acc[tt][1][1]));
            }
        }
        #pragma unroll
        for (int bi = 0; bi < 2; ++bi)
            #pragma unroll
            for (int oi = 0; oi < 2; ++oi) {
                int bo = (bb + bi * 4) * 16 + (oo + oi * 8);
                #pragma unroll
                for (int tt = 0; tt < 4; ++tt) {
                    int kk = k0 + tq * 4 + tt;
                    int ka = (kk == 0) ? 0 : NVOL - kk;
                    Z[(size_t)bo * NVOL + ka] = 0.5f * acc[tt][bi][oi];
                }
            }
    }
}

__global__ void __launch_bounds__(128) zmul_self_kernel(const float* __restrict__ X,
                                                        const float* __restrict__ Y,
                                                        float* __restrict__ Z) {
    const int bo = threadIdx.x, b = bo >> 4, o = bo & 15;
    const int k = NVOL / 2;
    float acc = 0.f;
    #pragma unroll
    for (int i = 0; i < 16; ++i)
        acc += X[(size_t)(b * 16 + i) * NVOL + k] * Y[(size_t)(i * 16 + o) * NVOL + k];
    Z[(size_t)bo * NVOL + k] = acc;
}

// ---------------------------------------------------------------------------
extern "C" void kernel_launch(void* const* d_in, const int* in_sizes, int n_in,
                              void* d_out, int out_size, void* d_ws, size_t ws_size,
                              hipStream_t stream) {
    const float* x = (const float*)d_in[0];     // [8,16,48,48,48]
    const float* w = (const float*)d_in[2];     // [16,16,12,12,12] compact corner
    float* out = (float*)d_out;                 // [8,16,48,48,48]

    float* HY  = (float*)d_ws;                  // 256*NVOL
    float* XA  = HY + (size_t)256 * NVOL;       // 128*NVOL
    float* XB  = XA + (size_t)128 * NVOL;       // 128*NVOL
    float* Ywh = XB;                            // 256*27648, aliases XB (dead before X dcomb)

    // ---- Y path ----
    cas_wh_kernel<12, 12><<<dim3(12, 256), 192, 0, stream>>>(w, Ywh, 1728, 144, 12, 27648, PLANE);
    cas_dcomb2<12><<<dim3(25, 256), 192, 0, stream>>>(Ywh, HY, 27648, PLANE, 0.5f);

    // ---- X path ----
    cas_wh48<<<dim3(12, 128), 192, 0, stream>>>(x, XA);
    cas_dcomb2<48><<<dim3(25, 128), 192, 0, stream>>>(XA, XB, NVOL, PLANE, 0.5f);

    // ---- Z contraction ----
    zmul_kernel<<<3456, 256, 0, stream>>>(XB, HY, XA);
    zmul_self_kernel<<<1, 128, 0, stream>>>(XB, HY, XA);

    // ---- out = DHT3(Z) / NVOL ----
    cas_wh48<<<dim3(12, 128), 192, 0, stream>>>(XA, XB);
    cas_dcomb2<48><<<dim3(25, 128), 192, 0, stream>>>(XB, out, NVOL, PLANE, 0.5f / (float)NVOL);
}